// Round 1
// baseline (143.055 us; speedup 1.0000x reference)
//
#include <hip/hip_runtime.h>

// Chamfer distance, B=16, N=M=4096, D=3, fp32.
// d(i,j) = |q_i - t_j|^2 = n_q + (n_t - 2 q.t)
// Inner loop per pair: 3 FMA + 1 min (query premultiplied by -2, targets
// packed as float4 [x,y,z,|t|^2]).

#define CB 16
#define CN 4096
#define CM 4096

__global__ __launch_bounds__(256) void pack_points(
    const float* __restrict__ x, float4* __restrict__ out, int total)
{
    int i = blockIdx.x * blockDim.x + threadIdx.x;
    if (i < total) {
        float a = x[3 * i + 0];
        float b = x[3 * i + 1];
        float c = x[3 * i + 2];
        out[i] = make_float4(a, b, c, a * a + b * b + c * c);
    }
}

// Block: 256 threads = 4 waves. 64 queries per block (one per lane).
// Wave w scans target chunk [w*1024, (w+1)*1024). LDS min-combine.
// grid: (4096/64, B, 2 directions)
__global__ __launch_bounds__(256) void chamfer_min(
    const float4* __restrict__ p1, const float4* __restrict__ p2,
    float* __restrict__ out)
{
    const int dir = blockIdx.z;          // 0: dist1 (q=x1,t=x2), 1: dist2
    const int b   = blockIdx.y;

    const float4* __restrict__ qry = dir ? (p2 + (size_t)b * CM) : (p1 + (size_t)b * CN);
    const float4* __restrict__ tgt = dir ? (p1 + (size_t)b * CN) : (p2 + (size_t)b * CM);
    float* __restrict__ o = out + (dir ? ((size_t)CB * CN + (size_t)b * CM)
                                       : ((size_t)b * CN));
    const int nt = dir ? CN : CM;        // 4096 either way

    const int lane = threadIdx.x & 63;
    // Force wave-uniformity into an SGPR so target loads can be scalar (s_load).
    const int wave = __builtin_amdgcn_readfirstlane(threadIdx.x >> 6);

    const int q = blockIdx.x * 64 + lane;
    const float4 Q = qry[q];
    const float m2x = -2.0f * Q.x;
    const float m2y = -2.0f * Q.y;
    const float m2z = -2.0f * Q.z;
    const float nq  = Q.w;

    const int chunk = nt >> 2;           // 1024
    const int j0 = wave * chunk;

    float best0 = 1e30f, best1 = 1e30f, best2 = 1e30f, best3 = 1e30f;

    #pragma unroll 4
    for (int j = j0; j < j0 + chunk; j += 4) {
        float4 t0 = tgt[j + 0];
        float4 t1 = tgt[j + 1];
        float4 t2 = tgt[j + 2];
        float4 t3 = tgt[j + 3];
        best0 = fminf(best0, fmaf(m2x, t0.x, fmaf(m2y, t0.y, fmaf(m2z, t0.z, t0.w))));
        best1 = fminf(best1, fmaf(m2x, t1.x, fmaf(m2y, t1.y, fmaf(m2z, t1.z, t1.w))));
        best2 = fminf(best2, fmaf(m2x, t2.x, fmaf(m2y, t2.y, fmaf(m2z, t2.z, t2.w))));
        best3 = fminf(best3, fmaf(m2x, t3.x, fmaf(m2y, t3.y, fmaf(m2z, t3.z, t3.w))));
    }
    float best = fminf(fminf(best0, best1), fminf(best2, best3));

    __shared__ float smem[4][64];
    smem[wave][lane] = best;
    __syncthreads();

    if (threadIdx.x < 64) {
        // wave 0, lane == threadIdx.x: this thread's Q/nq belongs to exactly
        // the query it writes.
        float v = fminf(fminf(smem[0][lane], smem[1][lane]),
                        fminf(smem[2][lane], smem[3][lane]));
        o[blockIdx.x * 64 + lane] = fmaxf(v + nq, 0.0f);
    }
}

extern "C" void kernel_launch(void* const* d_in, const int* in_sizes, int n_in,
                              void* d_out, int out_size, void* d_ws, size_t ws_size,
                              hipStream_t stream) {
    const float* x1 = (const float*)d_in[0];   // [B,N,3]
    const float* x2 = (const float*)d_in[1];   // [B,M,3]
    float* out = (float*)d_out;                // [B*N + B*M]

    float4* p1 = (float4*)d_ws;                         // B*N float4 = 1 MB
    float4* p2 = (float4*)((char*)d_ws + (size_t)CB * CN * sizeof(float4));

    const int tot1 = CB * CN;
    const int tot2 = CB * CM;
    pack_points<<<(tot1 + 255) / 256, 256, 0, stream>>>(x1, p1, tot1);
    pack_points<<<(tot2 + 255) / 256, 256, 0, stream>>>(x2, p2, tot2);

    dim3 grid(CN / 64, CB, 2);
    chamfer_min<<<grid, 256, 0, stream>>>(p1, p2, out);
}

// Round 2
// 128.385 us; speedup vs baseline: 1.1143x; 1.1143x over previous
//
#include <hip/hip_runtime.h>

// Chamfer distance, B=16, N=M=4096, D=3, fp32.
// d(i,j) = |q_i - t_j|^2 = n_q + (n_t - 2 q.t)
// Targets packed as float4 [x,y,z,|t|^2]; query premultiplied by -2.
// Register tiling: 4 queries per lane -> one wave-uniform target load
// amortized over 16 VALU ops (VMEM:VALU = 1:16).

#define CB 16
#define CN 4096
#define CM 4096
#define QPL 4          // queries per lane
#define WVS 8          // waves per block (512 threads)
#define QPB (64 * QPL) // queries per block = 256
#define TPW (CM / WVS) // targets per wave = 512

__global__ __launch_bounds__(256) void pack_all(
    const float* __restrict__ x1, const float* __restrict__ x2,
    float4* __restrict__ p, int tot1, int tot2)
{
    int i = blockIdx.x * blockDim.x + threadIdx.x;
    const float* src;
    int idx;
    if (i < tot1)            { src = x1; idx = i; }
    else if (i < tot1 + tot2){ src = x2; idx = i - tot1; }
    else return;
    float a = src[3 * idx + 0];
    float b = src[3 * idx + 1];
    float c = src[3 * idx + 2];
    p[i] = make_float4(a, b, c, a * a + b * b + c * c);
}

// grid: (CN/QPB, B, 2 dirs), block: 512 = 8 waves.
// Each wave scans its own 512-target chunk for all 256 of the block's
// queries (4 per lane). LDS min-combine across the 8 waves.
__global__ __launch_bounds__(512) void chamfer_min(
    const float4* __restrict__ p1, const float4* __restrict__ p2,
    float* __restrict__ out)
{
    const int dir = blockIdx.z;
    const int b   = blockIdx.y;

    const float4* __restrict__ qry = dir ? (p2 + (size_t)b * CM) : (p1 + (size_t)b * CN);
    const float4* __restrict__ tgt = dir ? (p1 + (size_t)b * CN) : (p2 + (size_t)b * CM);
    float* __restrict__ o = out + (dir ? ((size_t)CB * CN + (size_t)b * CM)
                                       : ((size_t)b * CN));

    const int lane = threadIdx.x & 63;
    const int wave = __builtin_amdgcn_readfirstlane(threadIdx.x >> 6);

    const int qbase = blockIdx.x * QPB + lane;

    float m2x[QPL], m2y[QPL], m2z[QPL], nqv[QPL];
    #pragma unroll
    for (int k = 0; k < QPL; ++k) {
        float4 Q = qry[qbase + 64 * k];
        m2x[k] = -2.0f * Q.x;
        m2y[k] = -2.0f * Q.y;
        m2z[k] = -2.0f * Q.z;
        nqv[k] = Q.w;
    }

    const int j0 = wave * TPW;

    float best[QPL][4];
    #pragma unroll
    for (int k = 0; k < QPL; ++k)
        #pragma unroll
        for (int u = 0; u < 4; ++u)
            best[k][u] = 1e30f;

    for (int j = j0; j < j0 + TPW; j += 4) {
        float4 t0 = tgt[j + 0];
        float4 t1 = tgt[j + 1];
        float4 t2 = tgt[j + 2];
        float4 t3 = tgt[j + 3];
        #pragma unroll
        for (int k = 0; k < QPL; ++k) {
            best[k][0] = fminf(best[k][0], fmaf(m2x[k], t0.x, fmaf(m2y[k], t0.y, fmaf(m2z[k], t0.z, t0.w))));
            best[k][1] = fminf(best[k][1], fmaf(m2x[k], t1.x, fmaf(m2y[k], t1.y, fmaf(m2z[k], t1.z, t1.w))));
            best[k][2] = fminf(best[k][2], fmaf(m2x[k], t2.x, fmaf(m2y[k], t2.y, fmaf(m2z[k], t2.z, t2.w))));
            best[k][3] = fminf(best[k][3], fmaf(m2x[k], t3.x, fmaf(m2y[k], t3.y, fmaf(m2z[k], t3.z, t3.w))));
        }
    }

    __shared__ float smem[WVS][QPL][64];
    #pragma unroll
    for (int k = 0; k < QPL; ++k) {
        float v = fminf(fminf(best[k][0], best[k][1]), fminf(best[k][2], best[k][3]));
        smem[wave][k][lane] = v + nqv[k];   // nq constant per query: min commutes
    }
    __syncthreads();

    if (threadIdx.x < QPB) {
        const int k = threadIdx.x >> 6;
        const int l = threadIdx.x & 63;
        float v = 1e30f;
        #pragma unroll
        for (int w = 0; w < WVS; ++w)
            v = fminf(v, smem[w][k][l]);
        o[blockIdx.x * QPB + threadIdx.x] = fmaxf(v, 0.0f);
    }
}

extern "C" void kernel_launch(void* const* d_in, const int* in_sizes, int n_in,
                              void* d_out, int out_size, void* d_ws, size_t ws_size,
                              hipStream_t stream) {
    const float* x1 = (const float*)d_in[0];   // [B,N,3]
    const float* x2 = (const float*)d_in[1];   // [B,M,3]
    float* out = (float*)d_out;

    float4* p1 = (float4*)d_ws;
    float4* p2 = p1 + (size_t)CB * CN;

    const int tot1 = CB * CN;
    const int tot2 = CB * CM;
    pack_all<<<(tot1 + tot2 + 255) / 256, 256, 0, stream>>>(x1, x2, p1, tot1, tot2);

    dim3 grid(CN / QPB, CB, 2);
    chamfer_min<<<grid, 512, 0, stream>>>(p1, p2, out);
}

// Round 3
// 117.185 us; speedup vs baseline: 1.2208x; 1.0956x over previous
//
#include <hip/hip_runtime.h>

// Chamfer distance, B=16, N=M=4096, D=3, fp32.
// d(i,j) = n_q + (n_t - 2 q.t); targets packed float4 [x,y,z,|t|^2],
// query premultiplied by -2. 4 queries/lane, 8 targets/iter (manual,
// unroll-pinned), fminf chains shaped for v_min3_f32 formation.
// __launch_bounds__(512,4) caps VGPRs at 128 -> 4 waves/SIMD.

#define CB 16
#define CN 4096
#define CM 4096
#define QPL 4          // queries per lane
#define WVS 8          // waves per block (512 threads)
#define QPB (64 * QPL) // queries per block = 256
#define TPW (CM / WVS) // targets per wave = 512
#define TGT 8          // targets per loop iteration

__global__ __launch_bounds__(256) void pack_all(
    const float* __restrict__ x1, const float* __restrict__ x2,
    float4* __restrict__ p, int tot1, int tot2)
{
    int i = blockIdx.x * blockDim.x + threadIdx.x;
    const float* src;
    int idx;
    if (i < tot1)            { src = x1; idx = i; }
    else if (i < tot1 + tot2){ src = x2; idx = i - tot1; }
    else return;
    float a = src[3 * idx + 0];
    float b = src[3 * idx + 1];
    float c = src[3 * idx + 2];
    p[i] = make_float4(a, b, c, a * a + b * b + c * c);
}

__global__ __launch_bounds__(512, 4) void chamfer_min(
    const float4* __restrict__ p1, const float4* __restrict__ p2,
    float* __restrict__ out)
{
    const int dir = blockIdx.z;
    const int b   = blockIdx.y;

    const float4* __restrict__ qry = dir ? (p2 + (size_t)b * CM) : (p1 + (size_t)b * CN);
    const float4* __restrict__ tgt = dir ? (p1 + (size_t)b * CN) : (p2 + (size_t)b * CM);
    float* __restrict__ o = out + (dir ? ((size_t)CB * CN + (size_t)b * CM)
                                       : ((size_t)b * CN));

    const int lane = threadIdx.x & 63;
    const int wave = __builtin_amdgcn_readfirstlane(threadIdx.x >> 6);

    const int qbase = blockIdx.x * QPB + lane;

    float m2x[QPL], m2y[QPL], m2z[QPL], nqv[QPL];
    #pragma unroll
    for (int k = 0; k < QPL; ++k) {
        float4 Q = qry[qbase + 64 * k];
        m2x[k] = -2.0f * Q.x;
        m2y[k] = -2.0f * Q.y;
        m2z[k] = -2.0f * Q.z;
        nqv[k] = Q.w;
    }

    // 2 running minima per query; combines written as fminf(a, fminf(b, best))
    // so the backend forms v_min3_f32.
    float best[QPL][2];
    #pragma unroll
    for (int k = 0; k < QPL; ++k) { best[k][0] = 1e30f; best[k][1] = 1e30f; }

    const float4* __restrict__ tp = tgt + wave * TPW;

    #pragma unroll 1
    for (int j = 0; j < TPW; j += TGT) {
        float4 t[TGT];
        #pragma unroll
        for (int u = 0; u < TGT; ++u) t[u] = tp[j + u];

        #pragma unroll
        for (int k = 0; k < QPL; ++k) {
            float d[TGT];
            #pragma unroll
            for (int u = 0; u < TGT; ++u)
                d[u] = fmaf(m2x[k], t[u].x,
                       fmaf(m2y[k], t[u].y,
                       fmaf(m2z[k], t[u].z, t[u].w)));
            best[k][0] = fminf(d[0], fminf(d[1], best[k][0]));
            best[k][1] = fminf(d[2], fminf(d[3], best[k][1]));
            best[k][0] = fminf(d[4], fminf(d[5], best[k][0]));
            best[k][1] = fminf(d[6], fminf(d[7], best[k][1]));
        }
    }

    __shared__ float smem[WVS][QPL][64];
    #pragma unroll
    for (int k = 0; k < QPL; ++k)
        smem[wave][k][lane] = fminf(best[k][0], best[k][1]) + nqv[k];
    __syncthreads();

    if (threadIdx.x < QPB) {
        const int k = threadIdx.x >> 6;
        const int l = threadIdx.x & 63;
        float v = smem[0][k][l];
        #pragma unroll
        for (int w = 1; w < WVS; w += 2)
            v = fminf(smem[w][k][l], fminf(smem[w + 1 < WVS ? w + 1 : w][k][l], v));
        o[blockIdx.x * QPB + threadIdx.x] = fmaxf(v, 0.0f);
    }
}

extern "C" void kernel_launch(void* const* d_in, const int* in_sizes, int n_in,
                              void* d_out, int out_size, void* d_ws, size_t ws_size,
                              hipStream_t stream) {
    const float* x1 = (const float*)d_in[0];   // [B,N,3]
    const float* x2 = (const float*)d_in[1];   // [B,M,3]
    float* out = (float*)d_out;

    float4* p1 = (float4*)d_ws;
    float4* p2 = p1 + (size_t)CB * CN;

    const int tot1 = CB * CN;
    const int tot2 = CB * CM;
    pack_all<<<(tot1 + tot2 + 255) / 256, 256, 0, stream>>>(x1, x2, p1, tot1, tot2);

    dim3 grid(CN / QPB, CB, 2);
    chamfer_min<<<grid, 512, 0, stream>>>(p1, p2, out);
}

// Round 4
// 109.891 us; speedup vs baseline: 1.3018x; 1.0664x over previous
//
#include <hip/hip_runtime.h>

// Chamfer distance, B=16, N=M=4096, D=3, fp32.
// d(i,j) = n_q + (n_t - 2 q.t).
// Targets pre-packed in PAIRS: group g = targets (2g,2g+1) stored as two
// float4s: [x0,x1,y0,y1], [z0,z1,w0,w1]  (w = |t|^2). This puts the
// (t0,t1) component pairs in even-aligned VGPR pairs straight out of
// global_load_dwordx4, feeding v_pk_fma_f32 (2 FMA/lane/instr) with no
// shuffles. Per 2 pairs: 3 v_pk_fma_f32 + 1 v_min3_f32 = 2 instr/pair.
// 4 queries/lane; register double-buffered target prefetch.

#define CB 16
#define CN 4096
#define CM 4096
#define QPL 4          // queries per lane
#define WVS 8          // waves per block (512 threads)
#define QPB (64 * QPL) // queries per block = 256
#define TPW (CM / WVS) // targets per wave = 512 (= 512 float4s, 64 groups*2)

typedef float v4f __attribute__((ext_vector_type(4)));
typedef float v2f __attribute__((ext_vector_type(2)));

__global__ __launch_bounds__(256) void pack_pairs(
    const float* __restrict__ x1, const float* __restrict__ x2,
    v4f* __restrict__ p, int pairs1, int pairs2)
{
    int i = blockIdx.x * blockDim.x + threadIdx.x;
    const float* s;
    int li;
    if (i < pairs1)               { s = x1; li = i; }
    else if (i < pairs1 + pairs2) { s = x2; li = i - pairs1; }
    else return;
    const float* r = s + 6 * li;
    float ax = r[0], ay = r[1], az = r[2];
    float bx = r[3], by = r[4], bz = r[5];
    p[2 * i]     = (v4f){ax, bx, ay, by};
    p[2 * i + 1] = (v4f){az, bz,
                         ax * ax + ay * ay + az * az,
                         bx * bx + by * by + bz * bz};
}

__device__ __forceinline__ void do8(const v4f t[8],
                                    const v2f mx2[QPL], const v2f my2[QPL],
                                    const v2f mz2[QPL], float best[QPL])
{
    #pragma unroll
    for (int g = 0; g < 4; ++g) {
        #pragma unroll
        for (int k = 0; k < QPL; ++k) {
            v2f d = t[2 * g + 1].zw;   // (w0, w1)
            asm("v_pk_fma_f32 %0, %1, %2, %0" : "+v"(d) : "v"(mz2[k]), "v"(t[2 * g + 1].xy));
            asm("v_pk_fma_f32 %0, %1, %2, %0" : "+v"(d) : "v"(my2[k]), "v"(t[2 * g].zw));
            asm("v_pk_fma_f32 %0, %1, %2, %0" : "+v"(d) : "v"(mx2[k]), "v"(t[2 * g].xy));
            asm("v_min3_f32 %0, %1, %2, %0" : "+v"(best[k]) : "v"(d.x), "v"(d.y));
        }
    }
}

// grid: (CN/QPB, B, 2), block 512 = 8 waves. Wave w scans targets
// [w*512, (w+1)*512) for the block's 256 queries (4/lane).
__global__ __launch_bounds__(512, 4) void chamfer_min(
    const v4f* __restrict__ p1, const v4f* __restrict__ p2,
    float* __restrict__ out)
{
    const int dir = blockIdx.z;
    const int b   = blockIdx.y;

    const v4f* __restrict__ qry = dir ? (p2 + (size_t)b * CM) : (p1 + (size_t)b * CN);
    const v4f* __restrict__ tgt = dir ? (p1 + (size_t)b * CN) : (p2 + (size_t)b * CM);
    float* __restrict__ o = out + (dir ? ((size_t)CB * CN + (size_t)b * CM)
                                       : ((size_t)b * CN));

    const int lane = threadIdx.x & 63;
    const int wave = __builtin_amdgcn_readfirstlane(threadIdx.x >> 6);

    const int qbase = blockIdx.x * QPB + lane;

    v2f mx2[QPL], my2[QPL], mz2[QPL];
    float nqv[QPL];
    #pragma unroll
    for (int k = 0; k < QPL; ++k) {
        int q = qbase + 64 * k;
        v4f g0 = qry[2 * (q >> 1)];     // (x0,x1,y0,y1)
        v4f g1 = qry[2 * (q >> 1) + 1]; // (z0,z1,w0,w1)
        int h = q & 1;
        float qx = h ? g0.y : g0.x;
        float qy = h ? g0.w : g0.z;
        float qz = h ? g1.y : g1.x;
        float qw = h ? g1.w : g1.z;
        mx2[k] = (v2f){-2.0f * qx, -2.0f * qx};
        my2[k] = (v2f){-2.0f * qy, -2.0f * qy};
        mz2[k] = (v2f){-2.0f * qz, -2.0f * qz};
        nqv[k] = qw;
    }

    float best[QPL];
    #pragma unroll
    for (int k = 0; k < QPL; ++k) best[k] = 1e30f;

    const v4f* __restrict__ tp = tgt + wave * TPW;  // 512 float4s

    v4f A[8], Bf[8];
    #pragma unroll
    for (int u = 0; u < 8; ++u) A[u] = tp[u];

    // 64 stages of 8 float4s (8 targets); 2-stage register double buffer.
    #pragma unroll 1
    for (int it = 0; it < 64; it += 2) {
        const int jb = (it + 1) * 8;
        #pragma unroll
        for (int u = 0; u < 8; ++u) Bf[u] = tp[jb + u];
        do8(A, mx2, my2, mz2, best);

        const int ja = (it + 2 < 64 ? it + 2 : 0) * 8;  // wrap: avoid OOB
        #pragma unroll
        for (int u = 0; u < 8; ++u) A[u] = tp[ja + u];
        do8(Bf, mx2, my2, mz2, best);
    }

    __shared__ float smem[WVS][QPL][64];
    #pragma unroll
    for (int k = 0; k < QPL; ++k)
        smem[wave][k][lane] = best[k] + nqv[k];
    __syncthreads();

    if (threadIdx.x < QPB) {
        const int k = threadIdx.x >> 6;
        const int l = threadIdx.x & 63;
        float v = smem[0][k][l];
        #pragma unroll
        for (int w = 1; w < WVS; ++w)
            v = fminf(v, smem[w][k][l]);
        o[blockIdx.x * QPB + threadIdx.x] = fmaxf(v, 0.0f);
    }
}

extern "C" void kernel_launch(void* const* d_in, const int* in_sizes, int n_in,
                              void* d_out, int out_size, void* d_ws, size_t ws_size,
                              hipStream_t stream) {
    const float* x1 = (const float*)d_in[0];   // [B,N,3]
    const float* x2 = (const float*)d_in[1];   // [B,M,3]
    float* out = (float*)d_out;

    v4f* p1 = (v4f*)d_ws;                  // CB*CN float4s
    v4f* p2 = p1 + (size_t)CB * CN;        // CB*CM float4s

    const int pairs1 = CB * CN / 2;
    const int pairs2 = CB * CM / 2;
    pack_pairs<<<(pairs1 + pairs2 + 255) / 256, 256, 0, stream>>>(x1, x2, p1, pairs1, pairs2);

    dim3 grid(CN / QPB, CB, 2);
    chamfer_min<<<grid, 512, 0, stream>>>(p1, p2, out);
}